// Round 8
// baseline (104.551 us; speedup 1.0000x reference)
//
#include <hip/hip_runtime.h>
#include <math.h>

typedef _Float16 half8  __attribute__((ext_vector_type(8)));
typedef _Float16 half4v __attribute__((ext_vector_type(4)));
typedef float    float4v __attribute__((ext_vector_type(4)));

#define BM   64      // rows per block -> 1024 blocks -> 4 blocks/CU resident
#define KDIM 256
#define BKF  128     // K-chunk (floats/halves)
#define XSTR 136     // halves per LDS row = BKF + 8 pad; 272 B, 16B-aligned
#define HSW  65      // fp32 h-tile stride: (r+k)%32 -> 2-way (free)

__global__ __launch_bounds__(256, 4)
void qc_fused(const float* __restrict__ x,
              const float* __restrict__ W1,
              const float* __restrict__ b1,
              const float* __restrict__ W2,
              const float* __restrict__ b2,
              const float* __restrict__ qw,
              float* __restrict__ out)
{
    __shared__ _Float16 xh[BM * XSTR];   // 17408 B; reused as fp32 hs[64*65] later
    __shared__ _Float16 wh[64 * XSTR];   // 17408 B
    __shared__ float w2s[256];
    __shared__ float b1s[64];
    __shared__ float b2s[4];
    __shared__ float trig[32];           // [layer][qubit][{cy,sy,cz,sz}]

    const int tid  = threadIdx.x;
    const int lane = tid & 63;
    const int wv   = tid >> 6;           // wave 0..3 -> rows wv*16..wv*16+15
    const int m    = lane & 15;
    const int q    = lane >> 4;
    const int row0 = blockIdx.x * BM;

    // ---- one-time per-block setup (before first sync) ----
    w2s[tid] = W2[tid];                  // 4*64 = 256
    if (tid < 64) b1s[tid] = b1[tid];
    if (tid < 4)  b2s[tid] = b2[tid];
    if (tid < 8) {
        int l = tid >> 2, i = tid & 3;
        float wy = qw[(l * 4 + i) * 2 + 0];
        float wz = qw[(l * 4 + i) * 2 + 1];
        float sy, cy, sz, cz;
        sincosf(0.5f * wy, &sy, &cy);
        sincosf(0.5f * wz, &sz, &cz);
        trig[(l * 4 + i) * 4 + 0] = cy;
        trig[(l * 4 + i) * 4 + 1] = sy;
        trig[(l * 4 + i) * 4 + 2] = cz;
        trig[(l * 4 + i) * 4 + 3] = sz;
    }

    float4v acc[4] = {};                 // 1 row-tile x 4 col-tiles, fp32

    const int sr  = tid >> 2, skq = tid & 3;   // staging: 64 rows x 4 k-quads (x and W identical geometry)

    for (int kc = 0; kc < KDIM; kc += BKF) {
        if (kc) __syncthreads();
        // ---- stage x chunk: 64 rows x 128 k, fp32 -> fp16 ----
        #pragma unroll
        for (int j = 0; j < 8; ++j) {
            int kf = 4 * skq + 16 * j;
            const float4v v = *(const float4v*)(x + (size_t)(row0 + sr) * KDIM + kc + kf);
            half4v h;
            h[0] = (_Float16)v[0]; h[1] = (_Float16)v[1];
            h[2] = (_Float16)v[2]; h[3] = (_Float16)v[3];
            *(half4v*)&xh[sr * XSTR + kf] = h;
        }
        // ---- stage W1 chunk: 64 rows x 128 k ----
        #pragma unroll
        for (int j = 0; j < 8; ++j) {
            int kf = 4 * skq + 16 * j;
            const float4v v = *(const float4v*)(W1 + (size_t)sr * KDIM + kc + kf);
            half4v h;
            h[0] = (_Float16)v[0]; h[1] = (_Float16)v[1];
            h[2] = (_Float16)v[2]; h[3] = (_Float16)v[3];
            *(half4v*)&wh[sr * XSTR + kf] = h;
        }
        __syncthreads();
        // ---- MFMA inner loop: 4 k-steps of 32 ----
        #pragma unroll
        for (int ks = 0; ks < 4; ++ks) {
            const int ko = ks * 32 + q * 8;
            half8 af = *(const half8*)&xh[(wv * 16 + m) * XSTR + ko];
            #pragma unroll
            for (int b = 0; b < 4; ++b) {
                half8 bf = *(const half8*)&wh[(16 * b + m) * XSTR + ko];
                acc[b] = __builtin_amdgcn_mfma_f32_16x16x32_f16(af, bf, acc[b], 0, 0, 0);
            }
        }
    }
    __syncthreads();

    // ---- epilogue: bias + relu -> hs (fp32, reuse xh region) ----
    float* hs = (float*)xh;
    #pragma unroll
    for (int b = 0; b < 4; ++b) {
        #pragma unroll
        for (int i = 0; i < 4; ++i) {
            int row = wv * 16 + 4 * q + i;    // C/D: row = quad*4+reg
            int col = 16 * b + m;             //      col = lane&15
            float v = acc[b][i] + b1s[col];
            hs[row * HSW + col] = fmaxf(v, 0.0f);
        }
    }
    __syncthreads();

    // ---- GEMM2 + tanh + quantum circuit: one thread per row ----
    if (tid < BM) {
        const int r = tid;
        float s0 = b2s[0], s1 = b2s[1], s2 = b2s[2], s3 = b2s[3];
        #pragma unroll 8
        for (int k = 0; k < 64; ++k) {
            float hv = hs[r * HSW + k];       // (r+k)%32 -> 2-way, free
            s0 = fmaf(hv, w2s[0 * 64 + k], s0);   // w2s broadcast, free
            s1 = fmaf(hv, w2s[1 * 64 + k], s1);
            s2 = fmaf(hv, w2s[2 * 64 + k], s2);
            s3 = fmaf(hv, w2s[3 * 64 + k], s3);
        }
        float ang[4] = { tanhf(s0), tanhf(s1), tanhf(s2), tanhf(s3) };

        float ca[4], sa[4];
        #pragma unroll
        for (int i = 0; i < 4; ++i)
            __sincosf(0.5f * ang[i], &sa[i], &ca[i]);

        // state idx = w0*8 + w1*4 + w2*2 + w3
        float re[16], im[16];
        #pragma unroll
        for (int idx = 0; idx < 16; ++idx) {
            re[idx] = (idx & 8 ? sa[0] : ca[0]) * (idx & 4 ? sa[1] : ca[1]) *
                      (idx & 2 ? sa[2] : ca[2]) * (idx & 1 ? sa[3] : ca[3]);
            im[idx] = 0.0f;
        }
        #pragma unroll
        for (int l = 0; l < 2; ++l) {
            #pragma unroll
            for (int i = 0; i < 4; ++i) {
                const float cy = trig[(l * 4 + i) * 4 + 0];
                const float sy = trig[(l * 4 + i) * 4 + 1];
                const float cz = trig[(l * 4 + i) * 4 + 2];
                const float sz = trig[(l * 4 + i) * 4 + 3];
                const int mq = 8 >> i;
                #pragma unroll
                for (int idx = 0; idx < 16; ++idx) {
                    if (!(idx & mq)) {
                        int j = idx | mq;
                        float ar = re[idx], ai = im[idx], br = re[j], bi = im[j];
                        re[idx] = fmaf(cy, ar, -sy * br);
                        im[idx] = fmaf(cy, ai, -sy * bi);
                        re[j]   = fmaf(sy, ar,  cy * br);
                        im[j]   = fmaf(sy, ai,  cy * bi);
                    }
                }
                #pragma unroll
                for (int idx = 0; idx < 16; ++idx) {
                    float sgn = (idx & mq) ? sz : -sz;
                    float ar = re[idx], ai = im[idx];
                    re[idx] = fmaf(ar, cz, -ai * sgn);
                    im[idx] = fmaf(ar, sgn, ai * cz);
                }
            }
            #pragma unroll
            for (int c = 0; c < 4; ++c) {
                int t  = (c + 1) & 3;
                int mc = 8 >> c, mt = 8 >> t;
                #pragma unroll
                for (int idx = 0; idx < 16; ++idx) {
                    if ((idx & mc) && !(idx & mt)) {
                        int j = idx | mt;
                        float tr = re[idx]; re[idx] = re[j]; re[j] = tr;
                        float ti = im[idx]; im[idx] = im[j]; im[j] = ti;
                    }
                }
            }
        }
        float z = 0.0f;
        #pragma unroll
        for (int idx = 0; idx < 16; ++idx) {
            float p = re[idx] * re[idx] + im[idx] * im[idx];
            z += (idx & 8) ? -p : p;
        }
        out[row0 + r] = z;
    }
}

extern "C" void kernel_launch(void* const* d_in, const int* in_sizes, int n_in,
                              void* d_out, int out_size, void* d_ws, size_t ws_size,
                              hipStream_t stream) {
    const float* x  = (const float*)d_in[0];
    const float* W1 = (const float*)d_in[1];
    const float* b1 = (const float*)d_in[2];
    const float* W2 = (const float*)d_in[3];
    const float* b2 = (const float*)d_in[4];
    const float* qw = (const float*)d_in[5];
    float* out = (float*)d_out;
    const int B = in_sizes[0] / KDIM;   // 65536
    qc_fused<<<B / BM, 256, 0, stream>>>(x, W1, b1, W2, b2, qw, out);
}